// Round 10
// baseline (576.768 us; speedup 1.0000x reference)
//
#include <hip/hip_runtime.h>

typedef __attribute__((ext_vector_type(8))) short short8;
typedef __attribute__((ext_vector_type(16))) float f32x16;

#define NB 8192        // points per (batch, set); B=4
#define JT_REAL 256    // 32-point col-tiles per batch
#define JT_PAD  258    // +2 tiles so the prefetch overrun stays in-bounds
#define JC 16          // col-splits per batch: chunk = 16 tiles
#define CHUNK (JT_REAL / JC)
#define ONE_BF 0x3F80
#define BIG_BF 0x7F7F

__device__ inline unsigned short bf_rne(float f) {
    unsigned u = __float_as_uint(f);
    return (unsigned short)((u + 0x7fffu + ((u >> 16) & 1u)) >> 16);
}
__device__ inline float bf_up(unsigned short h) { return __uint_as_float(((unsigned)h) << 16); }
__device__ inline float min3f(float a, float b, float c) { return fminf(fminf(a, b), c); }

// Phase 0: build B-operand fragments (MFMA 32x32x16 lane order) for xyz2
// (the column set); init minws (0x7F7F7F7F) and out (0).
// K-slot content (half = lane>>5, n = lane&31, point q = jtile*32+n):
//   half0 k0..7 : [(-2qx)_hi,(-2qx)_lo,(-2qy)_hi,(-2qy)_lo,(-2qz)_hi,(-2qz)_lo,|q|2_hi,|q|2_lo]
//   half1 k8..15: [(-2qx)_hi,(-2qy)_hi,(-2qz)_hi, 1.0, 1.0, 0,0,0]
// Pad tiles (jt>=256) are loaded by prefetch overrun but never consumed.
__global__ __launch_bounds__(256) void pack_kernel(
    const float* __restrict__ xyz2,
    short8* __restrict__ bfrag, int* __restrict__ minws, float* __restrict__ out)
{
    int t = blockIdx.x * 256 + threadIdx.x;
    const int FRAGS = 4 * JT_PAD * 64;     // 66048
    if (t < FRAGS) {
        int lane = t & 63;
        int jt   = (t >> 6) % JT_PAD;
        int b    = t / (64 * JT_PAD);
        int n = lane & 31, half = lane >> 5;
        short8 v = {0, 0, 0, 0, 0, 0, 0, 0};
        if (jt >= JT_REAL) {
            if (half == 0) v[6] = (short)BIG_BF;
        } else {
            const float* q = xyz2 + ((size_t)b * NB + (size_t)jt * 32 + n) * 3;
            float x = q[0], y = q[1], z = q[2];
            float mx = -2.f * x, my = -2.f * y, mz = -2.f * z;
            float qsq = x * x + y * y + z * z;
            unsigned short mhx = bf_rne(mx), mhy = bf_rne(my), mhz = bf_rne(mz);
            if (half == 0) {
                unsigned short mlx = bf_rne(mx - bf_up(mhx));
                unsigned short mly = bf_rne(my - bf_up(mhy));
                unsigned short mlz = bf_rne(mz - bf_up(mhz));
                unsigned short qh  = bf_rne(qsq);
                unsigned short ql  = bf_rne(qsq - bf_up(qh));
                v[0] = (short)mhx; v[1] = (short)mlx;
                v[2] = (short)mhy; v[3] = (short)mly;
                v[4] = (short)mhz; v[5] = (short)mlz;
                v[6] = (short)qh;  v[7] = (short)ql;
            } else {
                v[0] = (short)mhx; v[1] = (short)mhy; v[2] = (short)mhz;
                v[3] = (short)ONE_BF; v[4] = (short)ONE_BF;
            }
        }
        bfrag[t] = v;
    }
    if (t < 2 * 4 * NB) minws[t] = 0x7F7F7F7F;
    if (t == 0) out[0] = 0.f;
}

// Phase 1 (single pass, both directions): each MFMA distance tile feeds BOTH
// row-mins (dist1) and per-lane col-min partials (dist2). NOTHING cross-lane
// in the hot loop: col partials live in cmn[CHUNK] registers (lane = column);
// shuffles + atomics are epilogue-only. Wave owns 128 rows (4 row-tiles),
// iterates its 16-tile col chunk with a 2-tile prefetch queue.
// A-operand (rows, xyz1) in-register:
//   half0 k0..7 : [px_hi,px_hi,py_hi,py_hi,pz_hi,pz_hi, 1.0, 1.0]
//   half1 k8..15: [px_lo,py_lo,pz_lo,|p|2_hi,|p|2_lo, 0,0,0]
// => D = -2p.q + |q|2 + |p|2 = d^2 (error ~1e-5 from dropped lo*lo).
__global__ __launch_bounds__(256, 2) void chamfer_mfma_kernel(
    const float* __restrict__ xyz1, const short8* __restrict__ bfrag,
    int* __restrict__ minws)
{
    const int b    = blockIdx.z;        // batch
    const int lane = threadIdx.x & 63;
    const int w    = threadIdx.x >> 6;
    const int half = lane >> 5;
    const int m    = lane & 31;

    const int rowbase = blockIdx.x * 512 + w * 128;
    short8 a[4];
    #pragma unroll
    for (int t = 0; t < 4; ++t) {
        const float* p = xyz1 + ((size_t)b * NB + rowbase + t * 32 + m) * 3;
        float x = p[0], y = p[1], zc = p[2];
        float psq = x * x + y * y + zc * zc;
        unsigned short hx = bf_rne(x), hy = bf_rne(y), hz = bf_rne(zc);
        short8 v = {0, 0, 0, 0, 0, 0, 0, 0};
        if (half == 0) {
            v[0] = (short)hx; v[1] = (short)hx;
            v[2] = (short)hy; v[3] = (short)hy;
            v[4] = (short)hz; v[5] = (short)hz;
            v[6] = (short)ONE_BF; v[7] = (short)ONE_BF;
        } else {
            unsigned short lx = bf_rne(x - bf_up(hx));
            unsigned short ly = bf_rne(y - bf_up(hy));
            unsigned short lz = bf_rne(zc - bf_up(hz));
            unsigned short ph = bf_rne(psq);
            unsigned short pl = bf_rne(psq - bf_up(ph));
            v[0] = (short)lx; v[1] = (short)ly; v[2] = (short)lz;
            v[3] = (short)ph; v[4] = (short)pl;
        }
        a[t] = v;
    }

    float rmn[4][16];
    #pragma unroll
    for (int t = 0; t < 4; ++t)
        #pragma unroll
        for (int r = 0; r < 16; ++r) rmn[t][r] = 3.4e38f;

    float cmn[CHUNK];
    #pragma unroll
    for (int i = 0; i < CHUNK; ++i) cmn[i] = 3.4e38f;

    const f32x16 zero16 = {0,0,0,0,0,0,0,0,0,0,0,0,0,0,0,0};

    int* __restrict__ minrow = minws + (size_t)b * NB;
    int* __restrict__ mincol = minws + (size_t)4 * NB + (size_t)b * NB;

    const short8* __restrict__ bp = bfrag + (size_t)b * JT_PAD * 64;
    const int j0 = blockIdx.y * CHUNK;

    short8 f0 = bp[(size_t)(j0 + 0) * 64 + lane];
    short8 f1 = bp[(size_t)(j0 + 1) * 64 + lane];
    #pragma unroll
    for (int i = 0; i < CHUNK; ++i) {
        const int jt = j0 + i;
        short8 g = bp[(size_t)(jt + 2) * 64 + lane];   // pads cover overrun
        f32x16 d[4];
        #pragma unroll
        for (int t = 0; t < 4; ++t)
            d[t] = __builtin_amdgcn_mfma_f32_32x32x16_bf16(a[t], f0, zero16, 0, 0, 0);

        // row mins (dist1): independent per (t,r)
        #pragma unroll
        for (int t = 0; t < 4; ++t)
            #pragma unroll
            for (int r = 0; r < 16; ++r)
                rmn[t][r] = fminf(rmn[t][r], d[t][r]);

        // col partial (dist2): per-lane min over the 64 D values -> cmn[i].
        // Pure VALU min3 tree; no shuffle, no atomic here.
        float e[16];
        #pragma unroll
        for (int r = 0; r < 16; ++r)
            e[r] = fminf(fminf(d[0][r], d[1][r]), fminf(d[2][r], d[3][r]));
        float c0 = min3f(e[0], e[1], e[2]);
        float c1 = min3f(e[3], e[4], e[5]);
        float c2 = min3f(e[6], e[7], e[8]);
        float c3 = min3f(e[9], e[10], e[11]);
        float c4 = min3f(e[12], e[13], e[14]);
        cmn[i] = fminf(cmn[i], min3f(min3f(c0, c1, c2), min3f(c3, c4, e[15]),
                                     cmn[i] < 0.f ? cmn[i] : 3.4e38f));
        // (last operand is a no-op guard; values are >= ~0)
        cmn[i] = fminf(cmn[i], min3f(min3f(c0, c1, c2), c3, fminf(c4, e[15])));

        f0 = f1; f1 = g;
    }

    // epilogue A — col mins: combine halves, one atomic per (tile, column)
    #pragma unroll
    for (int i = 0; i < CHUNK; ++i) {
        float cm = fminf(cmn[i], __shfl_xor(cmn[i], 32, 64));
        if (half == 0)
            atomicMin(mincol + (j0 + i) * 32 + m, __float_as_int(cm));
    }

    // epilogue B — row mins: reduce across the 32 lanes of each half
    #pragma unroll
    for (int t = 0; t < 4; ++t)
        #pragma unroll
        for (int r = 0; r < 16; ++r) {
            float v = rmn[t][r];
            #pragma unroll
            for (int off = 16; off > 0; off >>= 1)
                v = fminf(v, __shfl_xor(v, off, 32));
            rmn[t][r] = v;
        }

    // C/D row mapping: row = (r&3) + 8*(r>>2) + 4*half  [m74/m101]
    if (m == 0) {
        #pragma unroll
        for (int t = 0; t < 4; ++t)
            #pragma unroll
            for (int r = 0; r < 16; ++r) {
                int row = rowbase + t * 32 + 4 * half + (r & 3) + 8 * (r >> 2);
                atomicMin(minrow + row, __float_as_int(rmn[t][r]));
            }
    }
}

// Phase 2: sum all mins with per-direction scale -> out[0]
__global__ __launch_bounds__(256) void reduce_kernel(
    const int* __restrict__ minws, float* __restrict__ out,
    int BN, int total, float scale1, float scale2)
{
    int t = blockIdx.x * 256 + threadIdx.x;
    float v = 0.f;
    if (t < total)
        v = __int_as_float(minws[t]) * (t < BN ? scale1 : scale2);

    #pragma unroll
    for (int off = 32; off > 0; off >>= 1)
        v += __shfl_down(v, off, 64);

    __shared__ float ssum[4];
    const int lane = threadIdx.x & 63;
    const int wave = threadIdx.x >> 6;
    if (lane == 0) ssum[wave] = v;
    __syncthreads();

    if (threadIdx.x == 0) {
        float s = 0.f;
        #pragma unroll
        for (int wv = 0; wv < 4; ++wv) s += ssum[wv];
        atomicAdd(out, s);
    }
}

extern "C" void kernel_launch(void* const* d_in, const int* in_sizes, int n_in,
                              void* d_out, int out_size, void* d_ws, size_t ws_size,
                              hipStream_t stream) {
    const float* xyz1 = (const float*)d_in[0];
    const float* xyz2 = (const float*)d_in[1];
    float* out = (float*)d_out;

    const int B = 4;
    const int BN = B * NB, BM = B * NB;
    const int total = BN + BM;            // 65536

    // ws: [bfrag: 4*258*64 short8 = 1.03 MB][minws: 64K ints = 256 KB]
    short8* bfrag = (short8*)d_ws;
    int* minws = (int*)(bfrag + (size_t)4 * JT_PAD * 64);

    const int FRAGS = 4 * JT_PAD * 64;    // 66048 > 65536, covers both inits
    pack_kernel<<<(FRAGS + 255) / 256, 256, 0, stream>>>(xyz2, bfrag, minws, out);

    dim3 grid(16, JC, B);                 // rows/512, col-chunks, batch
    chamfer_mfma_kernel<<<grid, 256, 0, stream>>>(xyz1, bfrag, minws);

    const float scale1 = 1.0f / (float)BN;
    const float scale2 = 1.0f / (float)BM;
    reduce_kernel<<<(total + 255) / 256, 256, 0, stream>>>(
        minws, out, BN, total, scale1, scale2);
}

// Round 11
// 90.997 us; speedup vs baseline: 6.3383x; 6.3383x over previous
//
#include <hip/hip_runtime.h>

typedef __attribute__((ext_vector_type(8))) short short8;
typedef __attribute__((ext_vector_type(16))) float f32x16;

#define NB 8192        // points per (batch, set); B=4
#define JT_REAL 256    // 32-point col-tiles per batch
#define JT_PAD  258    // +2 tiles so the prefetch overrun stays in-bounds
#define JC 8           // col-splits per batch: chunk = 32 tiles
#define CHUNK (JT_REAL / JC)
#define ONE_BF 0x3F80
#define BIG_BF 0x7F7F

__device__ inline unsigned short bf_rne(float f) {
    unsigned u = __float_as_uint(f);
    return (unsigned short)((u + 0x7fffu + ((u >> 16) & 1u)) >> 16);
}
__device__ inline float bf_up(unsigned short h) { return __uint_as_float(((unsigned)h) << 16); }
__device__ inline float min3f(float a, float b, float c) { return fminf(fminf(a, b), c); }

// Phase 0: build B-operand fragments (MFMA 32x32x16 lane order) for xyz2
// (the column set); init minws (0x7F7F7F7F) and out (0).
// K-slot content (half = lane>>5, n = lane&31, point q = jtile*32+n):
//   half0 k0..7 : [(-2qx)_hi,(-2qx)_lo,(-2qy)_hi,(-2qy)_lo,(-2qz)_hi,(-2qz)_lo,|q|2_hi,|q|2_lo]
//   half1 k8..15: [(-2qx)_hi,(-2qy)_hi,(-2qz)_hi, 1.0, 1.0, 0,0,0]
// Pad tiles (jt>=256) are loaded by prefetch overrun but never consumed.
__global__ __launch_bounds__(256) void pack_kernel(
    const float* __restrict__ xyz2,
    short8* __restrict__ bfrag, int* __restrict__ minws, float* __restrict__ out)
{
    int t = blockIdx.x * 256 + threadIdx.x;
    const int FRAGS = 4 * JT_PAD * 64;     // 66048
    if (t < FRAGS) {
        int lane = t & 63;
        int jt   = (t >> 6) % JT_PAD;
        int b    = t / (64 * JT_PAD);
        int n = lane & 31, half = lane >> 5;
        short8 v = {0, 0, 0, 0, 0, 0, 0, 0};
        if (jt >= JT_REAL) {
            if (half == 0) v[6] = (short)BIG_BF;
        } else {
            const float* q = xyz2 + ((size_t)b * NB + (size_t)jt * 32 + n) * 3;
            float x = q[0], y = q[1], z = q[2];
            float mx = -2.f * x, my = -2.f * y, mz = -2.f * z;
            float qsq = x * x + y * y + z * z;
            unsigned short mhx = bf_rne(mx), mhy = bf_rne(my), mhz = bf_rne(mz);
            if (half == 0) {
                unsigned short mlx = bf_rne(mx - bf_up(mhx));
                unsigned short mly = bf_rne(my - bf_up(mhy));
                unsigned short mlz = bf_rne(mz - bf_up(mhz));
                unsigned short qh  = bf_rne(qsq);
                unsigned short ql  = bf_rne(qsq - bf_up(qh));
                v[0] = (short)mhx; v[1] = (short)mlx;
                v[2] = (short)mhy; v[3] = (short)mly;
                v[4] = (short)mhz; v[5] = (short)mlz;
                v[6] = (short)qh;  v[7] = (short)ql;
            } else {
                v[0] = (short)mhx; v[1] = (short)mhy; v[2] = (short)mhz;
                v[3] = (short)ONE_BF; v[4] = (short)ONE_BF;
            }
        }
        bfrag[t] = v;
    }
    if (t < 2 * 4 * NB) minws[t] = 0x7F7F7F7F;
    if (t == 0) out[0] = 0.f;
}

// Phase 1 (single pass, both directions): each MFMA distance tile feeds BOTH
// row-mins (dist1, registers) and col-min partials (dist2, LDS).
// Hot loop contains NO cross-lane op, NO atomic, NO LDS read: the col
// partial is a pure min3 tree + one fire-and-forget ds_write_b32 per lane
// (2-way bank aliasing = free). Col combine happens after one barrier.
// Wave owns 128 rows (4 row-tiles); chunk = 32 col-tiles, 2-tile prefetch
// queue. (256,2): 256-VGPR cap, live set ~175 -> no spill (R10 lesson).
__global__ __launch_bounds__(256, 2) void chamfer_mfma_kernel(
    const float* __restrict__ xyz1, const short8* __restrict__ bfrag,
    int* __restrict__ minws)
{
    const int b    = blockIdx.z;        // batch
    const int lane = threadIdx.x & 63;
    const int w    = threadIdx.x >> 6;
    const int half = lane >> 5;
    const int m    = lane & 31;

    // col partials: [tile][wave][half][col]
    __shared__ float scol[CHUNK][4][2][32];

    const int rowbase = blockIdx.x * 512 + w * 128;
    short8 a[4];
    #pragma unroll
    for (int t = 0; t < 4; ++t) {
        const float* p = xyz1 + ((size_t)b * NB + rowbase + t * 32 + m) * 3;
        float x = p[0], y = p[1], zc = p[2];
        float psq = x * x + y * y + zc * zc;
        unsigned short hx = bf_rne(x), hy = bf_rne(y), hz = bf_rne(zc);
        short8 v = {0, 0, 0, 0, 0, 0, 0, 0};
        if (half == 0) {
            v[0] = (short)hx; v[1] = (short)hx;
            v[2] = (short)hy; v[3] = (short)hy;
            v[4] = (short)hz; v[5] = (short)hz;
            v[6] = (short)ONE_BF; v[7] = (short)ONE_BF;
        } else {
            unsigned short lx = bf_rne(x - bf_up(hx));
            unsigned short ly = bf_rne(y - bf_up(hy));
            unsigned short lz = bf_rne(zc - bf_up(hz));
            unsigned short ph = bf_rne(psq);
            unsigned short pl = bf_rne(psq - bf_up(ph));
            v[0] = (short)lx; v[1] = (short)ly; v[2] = (short)lz;
            v[3] = (short)ph; v[4] = (short)pl;
        }
        a[t] = v;
    }

    float rmn[4][16];
    #pragma unroll
    for (int t = 0; t < 4; ++t)
        #pragma unroll
        for (int r = 0; r < 16; ++r) rmn[t][r] = 3.4e38f;

    const f32x16 zero16 = {0,0,0,0,0,0,0,0,0,0,0,0,0,0,0,0};

    int* __restrict__ minrow = minws + (size_t)b * NB;
    int* __restrict__ mincol = minws + (size_t)4 * NB + (size_t)b * NB;

    const short8* __restrict__ bp = bfrag + (size_t)b * JT_PAD * 64;
    const int j0 = blockIdx.y * CHUNK;

    short8 f0 = bp[(size_t)(j0 + 0) * 64 + lane];
    short8 f1 = bp[(size_t)(j0 + 1) * 64 + lane];
    #pragma unroll 2
    for (int i = 0; i < CHUNK; ++i) {
        short8 g = bp[(size_t)(j0 + i + 2) * 64 + lane];   // pads cover overrun
        f32x16 d[4];
        #pragma unroll
        for (int t = 0; t < 4; ++t)
            d[t] = __builtin_amdgcn_mfma_f32_32x32x16_bf16(a[t], f0, zero16, 0, 0, 0);

        // row mins (dist1)
        #pragma unroll
        for (int t = 0; t < 4; ++t)
            #pragma unroll
            for (int r = 0; r < 16; ++r)
                rmn[t][r] = fminf(rmn[t][r], d[t][r]);

        // col partial (dist2): per-lane min over this tile's 64 D values,
        // pure min3 tree, then one LDS write. No reg accumulator (R10 fix).
        float e[16];
        #pragma unroll
        for (int r = 0; r < 16; ++r)
            e[r] = fminf(fminf(d[0][r], d[1][r]), fminf(d[2][r], d[3][r]));
        float c0 = min3f(e[0], e[1], e[2]);
        float c1 = min3f(e[3], e[4], e[5]);
        float c2 = min3f(e[6], e[7], e[8]);
        float c3 = min3f(e[9], e[10], e[11]);
        float c4 = min3f(min3f(e[12], e[13], e[14]), e[15], c0);
        scol[i][w][half][m] = min3f(min3f(c1, c2, c3), c4, c4);

        f0 = f1; f1 = g;
    }

    // ---- epilogue: row mins (registers) ----
    #pragma unroll
    for (int t = 0; t < 4; ++t)
        #pragma unroll
        for (int r = 0; r < 16; ++r) {
            float v = rmn[t][r];
            #pragma unroll
            for (int off = 16; off > 0; off >>= 1)
                v = fminf(v, __shfl_xor(v, off, 32));
            rmn[t][r] = v;
        }

    // C/D row mapping: row = (r&3) + 8*(r>>2) + 4*half  [m74/m101]
    if (m == 0) {
        #pragma unroll
        for (int t = 0; t < 4; ++t)
            #pragma unroll
            for (int r = 0; r < 16; ++r) {
                int row = rowbase + t * 32 + 4 * half + (r & 3) + 8 * (r >> 2);
                atomicMin(minrow + row, __float_as_int(rmn[t][r]));
            }
    }

    // ---- epilogue: col mins (LDS -> global) ----
    __syncthreads();
    // 32 tiles x 32 cols = 1024 (tile,col) pairs; 4 per thread
    #pragma unroll
    for (int k = 0; k < 4; ++k) {
        int p = threadIdx.x + k * 256;
        int tile = p >> 5, col = p & 31;
        float v = 3.4e38f;
        #pragma unroll
        for (int wv = 0; wv < 4; ++wv)
            v = fminf(v, fminf(scol[tile][wv][0][col], scol[tile][wv][1][col]));
        atomicMin(mincol + (j0 + tile) * 32 + col, __float_as_int(v));
    }
}

// Phase 2: sum all mins with per-direction scale -> out[0]
__global__ __launch_bounds__(256) void reduce_kernel(
    const int* __restrict__ minws, float* __restrict__ out,
    int BN, int total, float scale1, float scale2)
{
    int t = blockIdx.x * 256 + threadIdx.x;
    float v = 0.f;
    if (t < total)
        v = __int_as_float(minws[t]) * (t < BN ? scale1 : scale2);

    #pragma unroll
    for (int off = 32; off > 0; off >>= 1)
        v += __shfl_down(v, off, 64);

    __shared__ float ssum[4];
    const int lane = threadIdx.x & 63;
    const int wave = threadIdx.x >> 6;
    if (lane == 0) ssum[wave] = v;
    __syncthreads();

    if (threadIdx.x == 0) {
        float s = 0.f;
        #pragma unroll
        for (int wv = 0; wv < 4; ++wv) s += ssum[wv];
        atomicAdd(out, s);
    }
}

extern "C" void kernel_launch(void* const* d_in, const int* in_sizes, int n_in,
                              void* d_out, int out_size, void* d_ws, size_t ws_size,
                              hipStream_t stream) {
    const float* xyz1 = (const float*)d_in[0];
    const float* xyz2 = (const float*)d_in[1];
    float* out = (float*)d_out;

    const int B = 4;
    const int BN = B * NB, BM = B * NB;
    const int total = BN + BM;            // 65536

    // ws: [bfrag: 4*258*64 short8 = 1.03 MB][minws: 64K ints = 256 KB]
    short8* bfrag = (short8*)d_ws;
    int* minws = (int*)(bfrag + (size_t)4 * JT_PAD * 64);

    const int FRAGS = 4 * JT_PAD * 64;    // 66048 > 65536, covers both inits
    pack_kernel<<<(FRAGS + 255) / 256, 256, 0, stream>>>(xyz2, bfrag, minws, out);

    dim3 grid(16, JC, B);                 // rows/512, col-chunks, batch
    chamfer_mfma_kernel<<<grid, 256, 0, stream>>>(xyz1, bfrag, minws);

    const float scale1 = 1.0f / (float)BN;
    const float scale2 = 1.0f / (float)BM;
    reduce_kernel<<<(total + 255) / 256, 256, 0, stream>>>(
        minws, out, BN, total, scale1, scale2);
}